// Round 14
// baseline (227.071 us; speedup 1.0000x reference)
//
#include <hip/hip_runtime.h>
#include <cstdint>

typedef unsigned short u16;
typedef __attribute__((ext_vector_type(8))) short s16x8;
typedef __attribute__((ext_vector_type(8))) unsigned short u16x8;
typedef __attribute__((ext_vector_type(4))) float f32x4;
typedef __attribute__((ext_vector_type(16))) float f32x16;
typedef __attribute__((ext_vector_type(2))) unsigned uint2v;
typedef __attribute__((ext_vector_type(4))) unsigned uint4v;

#define CKF 0.18033688011f  // log2(e)/8, folded into Q projection

__device__ inline u16 f2bf(float f){
  union { float f; uint32_t u; } v; v.f = f;
  uint32_t r = v.u + 0x7fffu + ((v.u >> 16) & 1u);
  return (u16)(r >> 16);
}

__device__ inline f32x4 mfma16(s16x8 a, s16x8 b, f32x4 c){
  return __builtin_amdgcn_mfma_f32_16x16x32_bf16(a, b, c, 0, 0, 0);
}
__device__ inline f32x16 mfma32(s16x8 a, s16x8 b, f32x16 c){
  return __builtin_amdgcn_mfma_f32_32x32x16_bf16(a, b, c, 0, 0, 0);
}
__device__ inline unsigned cvtpk(float a, float b){
  unsigned r;
  asm("v_cvt_pk_bf16_f32 %0, %1, %2" : "=v"(r) : "v"(a), "v"(b));
  return r;
}
__device__ inline float exp2a(float x){
  float r;
  asm("v_exp_f32 %0, %1" : "=v"(r) : "v"(x));
  return r;
}
__device__ inline void glds16(const u16* g, u16* l){
  __builtin_amdgcn_global_load_lds((const __attribute__((address_space(1))) void*)g,
                                   (__attribute__((address_space(3))) void*)l, 16, 0, 0);
}
__device__ inline void glds4(const unsigned* g, unsigned* l){
  __builtin_amdgcn_global_load_lds((const __attribute__((address_space(1))) void*)g,
                                   (__attribute__((address_space(3))) void*)l, 4, 0, 0);
}

// ---------------------------------------------------------------- merged prep (unchanged)
struct PrepParams {
  const float* q; const float* k; const float* v;
  const int* mask; const float* mc;
  const float* W0; const float* W1; const float* W2; const float* W3;
  const float* Wc;
  u16* qo; u16* ko; u16* vo;
  u16* T0; u16* T1; u16* T2; u16* T3;
  unsigned* bits; float* part;
};

__global__ __launch_bounds__(256) void prep_kernel(PrepParams PP){
  __shared__ float shf[1056];
  int blk = blockIdx.x, tid = threadIdx.x;
  if (blk < 6144){
    int byy = blk >> 11, bxx = blk & 2047;
    const float* src = (byy == 0) ? PP.q : (byy == 1) ? PP.k : PP.v;
    u16* dst = (byy == 0) ? PP.qo : (byy == 1) ? PP.ko : PP.vo;
    size_t i = ((size_t)bxx * 256 + tid) * 8;
    float4 a = *(const float4*)(src + i);
    float4 b = *(const float4*)(src + i + 4);
    u16x8 o = { f2bf(a.x), f2bf(a.y), f2bf(a.z), f2bf(a.w),
                f2bf(b.x), f2bf(b.y), f2bf(b.z), f2bf(b.w) };
    *(u16x8*)(dst + i) = o;
  } else if (blk < 10240){
    int idx = blk - 6144;
    int bxx = idx & 31, byy = (idx >> 5) & 31, bzz = idx >> 10;
    const float* W = (bzz == 0) ? PP.W0 : (bzz == 1) ? PP.W1 : (bzz == 2) ? PP.W2 : PP.W3;
    u16* T = (bzz == 0) ? PP.T0 : (bzz == 1) ? PP.T1 : (bzz == 2) ? PP.T2 : PP.T3;
    float (*t)[33] = (float(*)[33])shf;
    int n0 = bxx * 32, k0 = byy * 32;
    int tx = tid & 31, ty = tid >> 5;
    #pragma unroll
    for (int j = 0; j < 4; j++)
      t[ty + j*8][tx] = W[(size_t)(k0 + ty + j*8) * 1024 + n0 + tx];
    __syncthreads();
    #pragma unroll
    for (int j = 0; j < 4; j++)
      T[(size_t)(n0 + ty + j*8) * 1024 + k0 + tx] = f2bf(t[tx][ty + j*8]);
  } else if (blk < 43008){
    size_t i = (size_t)(blk - 10240) * 256 + tid;
    int v = PP.mask[i];
    unsigned long long bal = __ballot(v != 0);
    int lane = tid & 63;
    if (lane == 0)       PP.bits[i >> 5] = (unsigned)bal;
    else if (lane == 32) PP.bits[i >> 5] = (unsigned)(bal >> 32);
  } else {
    int slice = blk - 43008;          // 0..15
    int k0 = slice * 64;
    float4 a0 = {0.f,0.f,0.f,0.f}, a1 = {0.f,0.f,0.f,0.f};
    const float* wp = PP.Wc + (size_t)k0 * 1024 + tid * 4;
    #pragma unroll 8
    for (int k = 0; k < 64; k++){
      float4 wv = *(const float4*)(wp + (size_t)k * 1024);
      float m0 = PP.mc[k0 + k], m1 = PP.mc[1024 + k0 + k];
      a0.x += m0 * wv.x; a0.y += m0 * wv.y; a0.z += m0 * wv.z; a0.w += m0 * wv.w;
      a1.x += m1 * wv.x; a1.y += m1 * wv.y; a1.z += m1 * wv.z; a1.w += m1 * wv.w;
    }
    *(float4*)(PP.part + ((size_t)slice * 2 + 0) * 1024 + tid * 4) = a0;
    *(float4*)(PP.part + ((size_t)slice * 2 + 1) * 1024 + tid * 4) = a1;
  }
}

__global__ __launch_bounds__(256) void ctxred_kernel(const float* __restrict__ part,
                                                     const float* __restrict__ bc,
                                                     float* __restrict__ ctx){
  int b = blockIdx.x, tid = threadIdx.x;
  float4 s = *(const float4*)(bc + tid * 4);
  #pragma unroll 4
  for (int sl = 0; sl < 16; sl++){
    float4 p = *(const float4*)(part + ((size_t)sl * 2 + b) * 1024 + tid * 4);
    s.x += p.x; s.y += p.y; s.z += p.z; s.w += p.w;
  }
  *(float4*)(ctx + (size_t)b * 1024 + tid * 4) = s;
}

// ---------------------------------------------------------------- GEMM (R8 exact, unchanged)
struct GemmParams {
  const u16* A0; const u16* A1; const u16* A2; const u16* A3;
  const u16* W0; const u16* W1; const u16* W2; const u16* W3;
  const float* b0; const float* b1; const float* b2;
  const float* ctx;
  u16* outQ; u16* outK; u16* outV; float* outX0; float* outX1;
  int which;
};

__global__ __launch_bounds__(256) void gemm_kernel(GemmParams P){
  int o = blockIdx.x + (blockIdx.y << 3) + (blockIdx.z << 8);
  int xcd = o & 7, j = o >> 3;
  int by = xcd + ((j & 3) << 3);
  int bx = (j >> 2) & 7;
  int bz = j >> 5;

  int z, kbase, nkt;
  const u16* A; const u16* W;
  if (P.which < 0){
    z = bz; kbase = 0; nkt = 32;
    if (z == 0){ A = P.A0; W = P.W0; }
    else if (z == 1){ A = P.A1; W = P.W1; }
    else { A = P.A2; W = P.W2; }
  } else {
    z = 3; kbase = bz * 512; nkt = 16;
    A = P.A3; W = P.W3;
  }
  int m0 = by * 128, n0 = bx * 128;
  __shared__ __align__(16) u16 sm[16384];
  int tid = threadIdx.x, lane = tid & 63, w = tid >> 6;
  int li = lane & 15, lq = lane >> 4;
  int wm = w >> 1, wn = w & 1;
  f32x4 zero = {0.f, 0.f, 0.f, 0.f};
  f32x4 acc[4][4];
  #pragma unroll
  for (int i = 0; i < 4; i++)
    #pragma unroll
    for (int jj = 0; jj < 4; jj++) acc[i][jj] = zero;

  int scolS = ((lane & 3) ^ ((lane >> 3) & 3)) << 3;
  int row0 = w * 16 + (lane >> 2);
  const u16* aS0 = A + (size_t)(m0 + row0) * 1024 + kbase + scolS;
  const u16* aS1 = aS0 + (size_t)64 * 1024;
  const u16* bS0 = W + (size_t)(n0 + row0) * 1024 + kbase + scolS;
  const u16* bS1 = bS0 + (size_t)64 * 1024;
  int aD0 = (w * 64) * 8, aD1 = (256 + w * 64) * 8;

  int aOff[4], bOff[4];
  #pragma unroll
  for (int mb = 0; mb < 4; mb++){
    int row = wm * 64 + mb * 16 + li;
    aOff[mb] = (row * 32 + ((lq ^ ((row >> 1) & 3)) << 3)) * 2;
  }
  #pragma unroll
  for (int nb = 0; nb < 4; nb++){
    int row = wn * 64 + nb * 16 + li;
    bOff[nb] = 8192 + (row * 32 + ((lq ^ ((row >> 1) & 3)) << 3)) * 2;
  }

  auto STAGE = [&](int ct){
    u16* Ab = &sm[ct * 8192];
    u16* Bb = &sm[ct * 8192 + 4096];
    glds16(aS0, Ab + aD0);
    glds16(aS1, Ab + aD1);
    glds16(bS0, Bb + aD0);
    glds16(bS1, Bb + aD1);
  };
  auto ADV = [&](){ aS0 += 32; aS1 += 32; bS0 += 32; bS1 += 32; };

  auto KITER = [&](int kt, int ct){
    __builtin_amdgcn_s_barrier();
    if (kt + 1 < nkt){
      STAGE(ct ^ 1); ADV();
      asm volatile("s_waitcnt vmcnt(4)" ::: "memory");
    } else {
      asm volatile("s_waitcnt vmcnt(0)" ::: "memory");
    }
    __builtin_amdgcn_sched_barrier(0);
    __builtin_amdgcn_s_barrier();
    const char* base = (const char*)sm + ct * 16384;
    s16x8 af[4], bfr[4];
    #pragma unroll
    for (int mb = 0; mb < 4; mb++) af[mb] = *(const s16x8*)(base + aOff[mb]);
    #pragma unroll
    for (int nb = 0; nb < 4; nb++) bfr[nb] = *(const s16x8*)(base + bOff[nb]);
    __builtin_amdgcn_s_setprio(1);
    #pragma unroll
    for (int mb = 0; mb < 4; mb++)
      #pragma unroll
      for (int nb = 0; nb < 4; nb++)
        acc[mb][nb] = mfma16(af[mb], bfr[nb], acc[mb][nb]);
    __builtin_amdgcn_s_setprio(0);
  };

  STAGE(0); ADV();
  for (int kt = 0; kt < nkt; kt += 2){
    KITER(kt, 0);
    KITER(kt + 1, 1);
  }

  if (z == 2){
    const float* bias = P.b2;
    __syncthreads();
    u16* Ot = sm;
    #pragma unroll
    for (int mb = 0; mb < 4; mb++){
      #pragma unroll
      for (int nb = 0; nb < 4; nb++){
        int colL = wn * 64 + nb * 16 + li;
        int rowB = wm * 64 + mb * 16 + lq * 4;
        float bcol = bias[n0 + colL];
        unsigned p01 = cvtpk(acc[mb][nb][0] + bcol, acc[mb][nb][1] + bcol);
        unsigned p23 = cvtpk(acc[mb][nb][2] + bcol, acc[mb][nb][3] + bcol);
        int ba = colL * 256 + ((rowB * 2) ^ ((colL & 7) << 4));
        *(unsigned*)((char*)Ot + ba) = p01;
        *(unsigned*)((char*)Ot + ba + 4) = p23;
      }
    }
    __syncthreads();
    int bq_ = m0 >> 11, srow0 = m0 & 2047;
    #pragma unroll
    for (int i = 0; i < 8; i++){
      int u = i * 256 + tid;
      int colL = u >> 4, sc = u & 15;
      int ba = colL * 256 + ((sc * 16) ^ ((colL & 7) << 4));
      u16x8 vv = *(const u16x8*)((char*)Ot + ba);
      *(u16x8*)(P.outV + (((size_t)(bq_ * 1024 + n0 + colL)) << 11) + srow0 + sc * 8) = vv;
    }
    return;
  }

  if (z == 3){
    float* Xo = (kbase == 0) ? P.outX0 : P.outX1;
    #pragma unroll
    for (int mb = 0; mb < 4; mb++){
      #pragma unroll
      for (int nb = 0; nb < 4; nb++){
        int col = n0 + wn * 64 + nb * 16 + li;
        #pragma unroll
        for (int r = 0; r < 4; r++){
          int row = m0 + wm * 64 + mb * 16 + lq * 4 + r;
          Xo[(size_t)row * 1024 + col] = acc[mb][nb][r];
        }
      }
    }
    return;
  }

  const float* bias = (z == 0) ? P.b0 : P.b1;
  #pragma unroll
  for (int mb = 0; mb < 4; mb++){
    #pragma unroll
    for (int nb = 0; nb < 4; nb++){
      int colL = wn * 64 + nb * 16 + li; int col = n0 + colL;
      float bcol = bias[col];
      #pragma unroll
      for (int r = 0; r < 4; r++){
        int row = m0 + wm * 64 + mb * 16 + lq * 4 + r;
        float v = acc[mb][nb][r] + bcol;
        if (z == 0){
          P.outQ[(size_t)row * 1024 + col] = f2bf(v * CKF);
        } else {
          v += P.ctx[(size_t)(row >> 11) * 1024 + col];
          P.outK[(size_t)row * 1024 + col] = f2bf(v);
        }
      }
    }
  }
}

// ---------------------------------------------------------------- flash attention, barrier-free:
// 4 independent waves/block (each owns 32 q-rows, full KV range). K/V fragments loaded
// DIRECTLY global->register (16B/lane); K double-buffered across tiles, V in-tile under
// softmax shadow. No LDS in the loop -> no barriers, no bank conflicts, waves slide freely.
__global__ __launch_bounds__(256) void attn_kernel(
    const u16* __restrict__ Qg, const u16* __restrict__ Kg, const u16* __restrict__ Vtg,
    const unsigned* __restrict__ mbits, u16* __restrict__ ctx2){
  __shared__ __align__(16) u16 Ot[8192];   // epilogue transpose only
  int tid = threadIdx.x, lane = tid & 63, w = tid >> 6;
  int l31 = lane & 31, hi = lane >> 5;
  int orig = blockIdx.x + (blockIdx.y << 4);
  int swz = (orig & 7) * 64 + (orig >> 3);
  int q0 = (swz & 15) * 128, bh = swz >> 4, b = bh >> 4, h = bh & 15;
  int qr = w * 32 + l31;

  s16x8 qf[4];
  {
    const u16* qp = Qg + (size_t)(b * 2048 + q0 + qr) * 1024 + h * 64 + hi * 8;
    #pragma unroll
    for (int ks = 0; ks < 4; ks++)
      qf[ks] = *(const s16x8*)(qp + ks * 16);
  }
  f32x16 ZERO;
  #pragma unroll
  for (int r = 0; r < 16; r++) ZERO[r] = 0.f;

  // per-lane fragment pointers
  const u16* pK0 = Kg + (size_t)(b * 2048 + l31) * 1024 + h * 64 + hi * 8;        // jj=0
  const u16* pK1 = pK0 + (size_t)32 * 1024;                                       // jj=1
  const u16* pV0 = Vtg + (((size_t)(bh * 64 + l31)) << 11) + hi * 8;              // dh=0
  const u16* pV1 = pV0 + ((size_t)32 << 11);                                      // dh=1
  const unsigned* pM = mbits + (size_t)(b * 2048 + q0 + qr) * 64;

  s16x8 kA[8], kB[8], vf[8];
  // preload tile 0 K
  #pragma unroll
  for (int ks = 0; ks < 4; ks++){
    kA[ks]     = *(const s16x8*)(pK0 + ks * 16);
    kA[4 + ks] = *(const s16x8*)(pK1 + ks * 16);
  }

  f32x16 accO[2];
  accO[0] = ZERO; accO[1] = ZERO;
  float ts0 = 0.f, ts1 = 0.f, ts2 = 0.f, ts3 = 0.f;

  auto ITER = [&](int t, s16x8* Kc, s16x8* Kn){
    // V loads for this tile (consumed ~400cy later, after softmax+pack)
    #pragma unroll
    for (int c = 0; c < 4; c++){
      vf[c]     = *(const s16x8*)(pV0 + c * 16);
      vf[4 + c] = *(const s16x8*)(pV1 + c * 16);
    }
    uint2v mw = *(const uint2v*)pM;
    pV0 += 64; pV1 += 64; pM += 2;
    // K prefetch for next tile
    if (t < 31){
      pK0 += 65536; pK1 += 65536;
      #pragma unroll
      for (int ks = 0; ks < 4; ks++){
        Kn[ks]     = *(const s16x8*)(pK0 + ks * 16);
        Kn[4 + ks] = *(const s16x8*)(pK1 + ks * 16);
      }
    }
    unsigned mh0 = mw[0] >> (hi << 2), mh1 = mw[1] >> (hi << 2);

    // ---- half jj=0: S0 -> softmax -> pf01 -> PV(c=0,1)
    f32x16 S0 = ZERO;
    __builtin_amdgcn_s_setprio(1);
    #pragma unroll
    for (int ks = 0; ks < 4; ks++) S0 = mfma32(Kc[ks], qf[ks], S0);
    __builtin_amdgcn_s_setprio(0);
    #pragma unroll
    for (int rg = 0; rg < 16; rg++){
      int pos = (rg & 3) + ((rg >> 2) << 3);
      float pv = exp2a(S0[rg]);
      pv = ((mh0 >> pos) & 1u) ? pv : 0.f;
      S0[rg] = pv;
    }
    ts0 += S0[0] + S0[4] + S0[8]  + S0[12];
    ts1 += S0[1] + S0[5] + S0[9]  + S0[13];
    ts2 += S0[2] + S0[6] + S0[10] + S0[14];
    ts3 += S0[3] + S0[7] + S0[11] + S0[15];
    s16x8 pf0, pf1;
    {
      unsigned A0 = cvtpk(S0[0], S0[1]),  A1 = cvtpk(S0[2], S0[3]);
      unsigned B0 = cvtpk(S0[4], S0[5]),  B1 = cvtpk(S0[6], S0[7]);
      uint2v r01 = __builtin_amdgcn_permlane32_swap(A0, B0, false, false);
      uint2v r23 = __builtin_amdgcn_permlane32_swap(A1, B1, false, false);
      uint4v u0 = { r01[0], r23[0], r01[1], r23[1] };
      pf0 = *(s16x8*)&u0;
      unsigned C0 = cvtpk(S0[8],  S0[9]),  C1 = cvtpk(S0[10], S0[11]);
      unsigned D0 = cvtpk(S0[12], S0[13]), D1 = cvtpk(S0[14], S0[15]);
      uint2v r45 = __builtin_amdgcn_permlane32_swap(C0, D0, false, false);
      uint2v r67 = __builtin_amdgcn_permlane32_swap(C1, D1, false, false);
      uint4v u1 = { r45[0], r67[0], r45[1], r67[1] };
      pf1 = *(s16x8*)&u1;
    }
    __builtin_amdgcn_s_setprio(1);
    accO[0] = mfma32(vf[0], pf0, accO[0]);
    accO[1] = mfma32(vf[4], pf0, accO[1]);
    accO[0] = mfma32(vf[1], pf1, accO[0]);
    accO[1] = mfma32(vf[5], pf1, accO[1]);
    __builtin_amdgcn_s_setprio(0);

    // ---- half jj=1: S1 -> softmax -> pf23 -> PV(c=2,3)
    f32x16 S1 = ZERO;
    __builtin_amdgcn_s_setprio(1);
    #pragma unroll
    for (int ks = 0; ks < 4; ks++) S1 = mfma32(Kc[4 + ks], qf[ks], S1);
    __builtin_amdgcn_s_setprio(0);
    #pragma unroll
    for (int rg = 0; rg < 16; rg++){
      int pos = (rg & 3) + ((rg >> 2) << 3);
      float pv = exp2a(S1[rg]);
      pv = ((mh1 >> pos) & 1u) ? pv : 0.f;
      S1[rg] = pv;
    }
    ts0 += S1[0] + S1[4] + S1[8]  + S1[12];
    ts1 += S1[1] + S1[5] + S1[9]  + S1[13];
    ts2 += S1[2] + S1[6] + S1[10] + S1[14];
    ts3 += S1[3] + S1[7] + S1[11] + S1[15];
    s16x8 pf2, pf3;
    {
      unsigned A0 = cvtpk(S1[0], S1[1]),  A1 = cvtpk(S1[2], S1[3]);
      unsigned B0 = cvtpk(S1[4], S1[5]),  B1 = cvtpk(S1[6], S1[7]);
      uint2v r01 = __builtin_amdgcn_permlane32_swap(A0, B0, false, false);
      uint2v r23 = __builtin_amdgcn_permlane32_swap(A1, B1, false, false);
      uint4v u2 = { r01[0], r23[0], r01[1], r23[1] };
      pf2 = *(s16x8*)&u2;
      unsigned C0 = cvtpk(S1[8],  S1[9]),  C1 = cvtpk(S1[10], S1[11]);
      unsigned D0 = cvtpk(S1[12], S1[13]), D1 = cvtpk(S1[14], S1[15]);
      uint2v r45 = __builtin_amdgcn_permlane32_swap(C0, D0, false, false);
      uint2v r67 = __builtin_amdgcn_permlane32_swap(C1, D1, false, false);
      uint4v u3 = { r45[0], r67[0], r45[1], r67[1] };
      pf3 = *(s16x8*)&u3;
    }
    __builtin_amdgcn_s_setprio(1);
    accO[0] = mfma32(vf[2], pf2, accO[0]);
    accO[1] = mfma32(vf[6], pf2, accO[1]);
    accO[0] = mfma32(vf[3], pf3, accO[0]);
    accO[1] = mfma32(vf[7], pf3, accO[1]);
    __builtin_amdgcn_s_setprio(0);
  };

  for (int t = 0; t < 32; t += 2){
    ITER(t, kA, kB);
    ITER(t + 1, kB, kA);
  }

  // single end-of-loop lsum reduction (static softmax: pure sums)
  float lsum = (ts0 + ts1) + (ts2 + ts3);
  lsum += __shfl_xor(lsum, 32, 64);
  float inv = 1.f / lsum;

  // transpose O^T through LDS, coalesced store
  #pragma unroll
  for (int dh = 0; dh < 2; dh++){
    #pragma unroll
    for (int rg = 0; rg < 16; rg += 2){
      int dk = dh * 32 + (rg & 3) + ((rg >> 2) << 3) + (hi << 2);
      unsigned pk = cvtpk(accO[dh][rg] * inv, accO[dh][rg + 1] * inv);
      *(unsigned*)&Ot[qr * 64 + (((dk >> 3) ^ (qr & 7)) << 3) + (dk & 7)] = pk;
    }
  }
  __syncthreads();
  #pragma unroll
  for (int i = 0; i < 4; i++){
    int u = i * 256 + tid, row = u >> 3, slot = u & 7;
    u16x8 vv = *(const u16x8*)&Ot[row * 64 + ((slot ^ (row & 7)) << 3)];
    *(u16x8*)(ctx2 + (size_t)(b * 2048 + q0 + row) * 1024 + h * 64 + slot * 8) = vv;
  }
}

// ---------------------------------------------------------------- LayerNorm of (X0 + X1 + query + bo)
__global__ __launch_bounds__(256) void ln_kernel(const float* __restrict__ X0,
                                                 const float* __restrict__ X1,
                                                 const float* __restrict__ qres,
                                                 const float* __restrict__ bo,
                                                 const float* __restrict__ g,
                                                 const float* __restrict__ bb,
                                                 float* __restrict__ out){
  size_t row = blockIdx.x;
  int tid = threadIdx.x;
  float4 a = *(const float4*)(X0 + row * 1024 + tid * 4);
  float4 c = *(const float4*)(X1 + row * 1024 + tid * 4);
  float4 q = *(const float4*)(qres + row * 1024 + tid * 4);
  float4 bv = *(const float4*)(bo + tid * 4);
  float4 v;
  v.x = a.x + c.x + q.x + bv.x;
  v.y = a.y + c.y + q.y + bv.y;
  v.z = a.z + c.z + q.z + bv.z;
  v.w = a.w + c.w + q.w + bv.w;
  float s = v.x + v.y + v.z + v.w;
  float s2 = v.x*v.x + v.y*v.y + v.z*v.z + v.w*v.w;
  #pragma unroll
  for (int o = 1; o < 64; o <<= 1){
    s += __shfl_xor(s, o, 64);
    s2 += __shfl_xor(s2, o, 64);
  }
  __shared__ float rs[4], rs2[4];
  int w = tid >> 6;
  if ((tid & 63) == 0){ rs[w] = s; rs2[w] = s2; }
  __syncthreads();
  s = rs[0] + rs[1] + rs[2] + rs[3];
  s2 = rs2[0] + rs2[1] + rs2[2] + rs2[3];
  float mu = s * (1.f / 1024.f);
  float var = s2 * (1.f / 1024.f) - mu * mu;
  float rstd = rsqrtf(var + 1e-5f);
  float4 gg = *(const float4*)(g + tid * 4);
  float4 bt = *(const float4*)(bb + tid * 4);
  float4 o;
  o.x = (v.x - mu) * rstd * gg.x + bt.x;
  o.y = (v.y - mu) * rstd * gg.y + bt.y;
  o.z = (v.z - mu) * rstd * gg.z + bt.z;
  o.w = (v.w - mu) * rstd * gg.w + bt.w;
  *(float4*)(out + row * 1024 + tid * 4) = o;
}

// ----------------------------------------------------------------
extern "C" void kernel_launch(void* const* d_in, const int* in_sizes, int n_in,
                              void* d_out, int out_size, void* d_ws, size_t ws_size,
                              hipStream_t stream){
  const float* query = (const float*)d_in[0];
  const float* key_  = (const float*)d_in[1];
  const float* value = (const float*)d_in[2];
  const int*   mask  = (const int*)d_in[3];
  const float* mc    = (const float*)d_in[4];
  const float* Wq = (const float*)d_in[5];  const float* bq = (const float*)d_in[6];
  const float* Wk = (const float*)d_in[7];  const float* bk = (const float*)d_in[8];
  const float* Wv = (const float*)d_in[9];  const float* bv = (const float*)d_in[10];
  const float* Wo = (const float*)d_in[11]; const float* bo = (const float*)d_in[12];
  const float* Wc = (const float*)d_in[13]; const float* bc = (const float*)d_in[14];
  const float* lng = (const float*)d_in[15]; const float* lnb = (const float*)d_in[16];
  float* outp = (float*)d_out;
  uint8_t* ws = (uint8_t*)d_ws;
  const size_t MB = (size_t)1 << 20;
  if (ws_size < 58 * MB) return;

  u16* q_bf = (u16*)(ws + 0);
  u16* k_bf = (u16*)(ws + 8 * MB);
  u16* v_bf = (u16*)(ws + 16 * MB);
  float* X0 = (float*)(ws + 8 * MB);
  u16* Qb   = (u16*)(ws + 24 * MB);
  u16* Kb   = (u16*)(ws + 32 * MB);
  float* X1 = (float*)(ws + 32 * MB);
  u16* Vt   = (u16*)(ws + 40 * MB);
  u16* Wqt  = (u16*)(ws + 48 * MB);
  u16* Wkt  = (u16*)(ws + 50 * MB);
  u16* Wvt  = (u16*)(ws + 52 * MB);
  u16* Wot  = (u16*)(ws + 54 * MB);
  unsigned* mbits = (unsigned*)(ws + 56 * MB);
  float* ctxf = (float*)(ws + 57 * MB);
  float* ctxpart = (float*)(ws + 57 * MB + 65536);
  u16* ctx2 = q_bf;

  PrepParams PP;
  PP.q = query; PP.k = key_; PP.v = value; PP.mask = mask; PP.mc = mc;
  PP.W0 = Wq; PP.W1 = Wk; PP.W2 = Wv; PP.W3 = Wo; PP.Wc = Wc;
  PP.qo = q_bf; PP.ko = k_bf; PP.vo = v_bf;
  PP.T0 = Wqt; PP.T1 = Wkt; PP.T2 = Wvt; PP.T3 = Wot;
  PP.bits = mbits; PP.part = ctxpart;
  prep_kernel<<<43024, 256, 0, stream>>>(PP);

  ctxred_kernel<<<2, 256, 0, stream>>>(ctxpart, bc, ctxf);

  GemmParams gp;
  gp.A0 = q_bf; gp.A1 = k_bf; gp.A2 = v_bf; gp.A3 = ctx2;
  gp.W0 = Wqt;  gp.W1 = Wkt;  gp.W2 = Wvt;  gp.W3 = Wot;
  gp.b0 = bq;   gp.b1 = bk;   gp.b2 = bv;
  gp.ctx = ctxf;
  gp.outQ = Qb; gp.outK = Kb; gp.outV = Vt; gp.outX0 = X0; gp.outX1 = X1;
  gp.which = -1;
  gemm_kernel<<<dim3(8, 32, 3), 256, 0, stream>>>(gp);

  attn_kernel<<<dim3(16, 32), 256, 0, stream>>>(Qb, Kb, Vt, mbits, ctx2);

  gp.which = 3;
  gemm_kernel<<<dim3(8, 32, 2), 256, 0, stream>>>(gp);

  ln_kernel<<<4096, 256, 0, stream>>>(X0, X1, query, bo, lng, lnb, outp);
}

// Round 15
// 153.050 us; speedup vs baseline: 1.4836x; 1.4836x over previous
//
#include <hip/hip_runtime.h>
#include <cstdint>

typedef unsigned short u16;
typedef __attribute__((ext_vector_type(8))) short s16x8;
typedef __attribute__((ext_vector_type(8))) unsigned short u16x8;
typedef __attribute__((ext_vector_type(4))) float f32x4;
typedef __attribute__((ext_vector_type(16))) float f32x16;
typedef __attribute__((ext_vector_type(2))) unsigned uint2v;
typedef __attribute__((ext_vector_type(4))) unsigned uint4v;

#define CKF 0.18033688011f  // log2(e)/8, folded into Q projection

__device__ inline u16 f2bf(float f){
  union { float f; uint32_t u; } v; v.f = f;
  uint32_t r = v.u + 0x7fffu + ((v.u >> 16) & 1u);
  return (u16)(r >> 16);
}

__device__ inline f32x4 mfma16(s16x8 a, s16x8 b, f32x4 c){
  return __builtin_amdgcn_mfma_f32_16x16x32_bf16(a, b, c, 0, 0, 0);
}
__device__ inline f32x16 mfma32(s16x8 a, s16x8 b, f32x16 c){
  return __builtin_amdgcn_mfma_f32_32x32x16_bf16(a, b, c, 0, 0, 0);
}
__device__ inline unsigned cvtpk(float a, float b){
  unsigned r;
  asm("v_cvt_pk_bf16_f32 %0, %1, %2" : "=v"(r) : "v"(a), "v"(b));
  return r;
}
__device__ inline float exp2a(float x){
  float r;
  asm("v_exp_f32 %0, %1" : "=v"(r) : "v"(x));
  return r;
}
__device__ inline void glds16(const u16* g, u16* l){
  __builtin_amdgcn_global_load_lds((const __attribute__((address_space(1))) void*)g,
                                   (__attribute__((address_space(3))) void*)l, 16, 0, 0);
}
__device__ inline void glds4(const unsigned* g, unsigned* l){
  __builtin_amdgcn_global_load_lds((const __attribute__((address_space(1))) void*)g,
                                   (__attribute__((address_space(3))) void*)l, 4, 0, 0);
}

// ---------------------------------------------------------------- merged prep (unchanged)
struct PrepParams {
  const float* q; const float* k; const float* v;
  const int* mask; const float* mc;
  const float* W0; const float* W1; const float* W2; const float* W3;
  const float* Wc;
  u16* qo; u16* ko; u16* vo;
  u16* T0; u16* T1; u16* T2; u16* T3;
  unsigned* bits; float* part;
};

__global__ __launch_bounds__(256) void prep_kernel(PrepParams PP){
  __shared__ float shf[1056];
  int blk = blockIdx.x, tid = threadIdx.x;
  if (blk < 6144){
    int byy = blk >> 11, bxx = blk & 2047;
    const float* src = (byy == 0) ? PP.q : (byy == 1) ? PP.k : PP.v;
    u16* dst = (byy == 0) ? PP.qo : (byy == 1) ? PP.ko : PP.vo;
    size_t i = ((size_t)bxx * 256 + tid) * 8;
    float4 a = *(const float4*)(src + i);
    float4 b = *(const float4*)(src + i + 4);
    u16x8 o = { f2bf(a.x), f2bf(a.y), f2bf(a.z), f2bf(a.w),
                f2bf(b.x), f2bf(b.y), f2bf(b.z), f2bf(b.w) };
    *(u16x8*)(dst + i) = o;
  } else if (blk < 10240){
    int idx = blk - 6144;
    int bxx = idx & 31, byy = (idx >> 5) & 31, bzz = idx >> 10;
    const float* W = (bzz == 0) ? PP.W0 : (bzz == 1) ? PP.W1 : (bzz == 2) ? PP.W2 : PP.W3;
    u16* T = (bzz == 0) ? PP.T0 : (bzz == 1) ? PP.T1 : (bzz == 2) ? PP.T2 : PP.T3;
    float (*t)[33] = (float(*)[33])shf;
    int n0 = bxx * 32, k0 = byy * 32;
    int tx = tid & 31, ty = tid >> 5;
    #pragma unroll
    for (int j = 0; j < 4; j++)
      t[ty + j*8][tx] = W[(size_t)(k0 + ty + j*8) * 1024 + n0 + tx];
    __syncthreads();
    #pragma unroll
    for (int j = 0; j < 4; j++)
      T[(size_t)(n0 + ty + j*8) * 1024 + k0 + tx] = f2bf(t[tx][ty + j*8]);
  } else if (blk < 43008){
    size_t i = (size_t)(blk - 10240) * 256 + tid;
    int v = PP.mask[i];
    unsigned long long bal = __ballot(v != 0);
    int lane = tid & 63;
    if (lane == 0)       PP.bits[i >> 5] = (unsigned)bal;
    else if (lane == 32) PP.bits[i >> 5] = (unsigned)(bal >> 32);
  } else {
    int slice = blk - 43008;          // 0..15
    int k0 = slice * 64;
    float4 a0 = {0.f,0.f,0.f,0.f}, a1 = {0.f,0.f,0.f,0.f};
    const float* wp = PP.Wc + (size_t)k0 * 1024 + tid * 4;
    #pragma unroll 8
    for (int k = 0; k < 64; k++){
      float4 wv = *(const float4*)(wp + (size_t)k * 1024);
      float m0 = PP.mc[k0 + k], m1 = PP.mc[1024 + k0 + k];
      a0.x += m0 * wv.x; a0.y += m0 * wv.y; a0.z += m0 * wv.z; a0.w += m0 * wv.w;
      a1.x += m1 * wv.x; a1.y += m1 * wv.y; a1.z += m1 * wv.z; a1.w += m1 * wv.w;
    }
    *(float4*)(PP.part + ((size_t)slice * 2 + 0) * 1024 + tid * 4) = a0;
    *(float4*)(PP.part + ((size_t)slice * 2 + 1) * 1024 + tid * 4) = a1;
  }
}

__global__ __launch_bounds__(256) void ctxred_kernel(const float* __restrict__ part,
                                                     const float* __restrict__ bc,
                                                     float* __restrict__ ctx){
  int b = blockIdx.x, tid = threadIdx.x;
  float4 s = *(const float4*)(bc + tid * 4);
  #pragma unroll 4
  for (int sl = 0; sl < 16; sl++){
    float4 p = *(const float4*)(part + ((size_t)sl * 2 + b) * 1024 + tid * 4);
    s.x += p.x; s.y += p.y; s.z += p.z; s.w += p.w;
  }
  *(float4*)(ctx + (size_t)b * 1024 + tid * 4) = s;
}

// ---------------------------------------------------------------- GEMM: BM=128 BN=128 BK=32,
// TRIPLE-buffered, ONE barrier per kt (stage target (kt+1)%3 last read at kt-2).
struct GemmParams {
  const u16* A0; const u16* A1; const u16* A2; const u16* A3;
  const u16* W0; const u16* W1; const u16* W2; const u16* W3;
  const float* b0; const float* b1; const float* b2;
  const float* ctx;
  u16* outQ; u16* outK; u16* outV; float* outX0; float* outX1;
  int which;
};

__global__ __launch_bounds__(256) void gemm_kernel(GemmParams P){
  int o = blockIdx.x + (blockIdx.y << 3) + (blockIdx.z << 8);
  int xcd = o & 7, j = o >> 3;
  int by = xcd + ((j & 3) << 3);
  int bx = (j >> 2) & 7;
  int bz = j >> 5;

  int z, kbase, nkt;
  const u16* A; const u16* W;
  if (P.which < 0){
    z = bz; kbase = 0; nkt = 32;
    if (z == 0){ A = P.A0; W = P.W0; }
    else if (z == 1){ A = P.A1; W = P.W1; }
    else { A = P.A2; W = P.W2; }
  } else {
    z = 3; kbase = bz * 512; nkt = 16;
    A = P.A3; W = P.W3;
  }
  int m0 = by * 128, n0 = bx * 128;
  __shared__ __align__(16) u16 sm[24576];   // 3 bufs x 8192 u16 (A 0..4095, B 4096..8191)
  int tid = threadIdx.x, lane = tid & 63, w = tid >> 6;
  int li = lane & 15, lq = lane >> 4;
  int wm = w >> 1, wn = w & 1;
  f32x4 zero = {0.f, 0.f, 0.f, 0.f};
  f32x4 acc[4][4];
  #pragma unroll
  for (int i = 0; i < 4; i++)
    #pragma unroll
    for (int jj = 0; jj < 4; jj++) acc[i][jj] = zero;

  int scolS = ((lane & 3) ^ ((lane >> 3) & 3)) << 3;
  int row0 = w * 16 + (lane >> 2);
  const u16* aS0 = A + (size_t)(m0 + row0) * 1024 + kbase + scolS;
  const u16* aS1 = aS0 + (size_t)64 * 1024;
  const u16* bS0 = W + (size_t)(n0 + row0) * 1024 + kbase + scolS;
  const u16* bS1 = bS0 + (size_t)64 * 1024;
  int aD0 = (w * 64) * 8, aD1 = (256 + w * 64) * 8;

  int aOff[4], bOff[4];
  #pragma unroll
  for (int mb = 0; mb < 4; mb++){
    int row = wm * 64 + mb * 16 + li;
    aOff[mb] = (row * 32 + ((lq ^ ((row >> 1) & 3)) << 3)) * 2;
  }
  #pragma unroll
  for (int nb = 0; nb < 4; nb++){
    int row = wn * 64 + nb * 16 + li;
    bOff[nb] = 8192 + (row * 32 + ((lq ^ ((row >> 1) & 3)) << 3)) * 2;
  }

  auto STAGE = [&](int ct){
    u16* Ab = &sm[ct * 8192];
    u16* Bb = &sm[ct * 8192 + 4096];
    glds16(aS0, Ab + aD0);
    glds16(aS1, Ab + aD1);
    glds16(bS0, Bb + aD0);
    glds16(bS1, Bb + aD1);
    aS0 += 32; aS1 += 32; bS0 += 32; bS1 += 32;
  };

  auto KITER = [&](int kt, int ct, int cn){
    if (kt + 1 < nkt){
      STAGE(cn);
      asm volatile("s_waitcnt vmcnt(4)" ::: "memory");  // older 4 (buf ct) landed
    } else {
      asm volatile("s_waitcnt vmcnt(0)" ::: "memory");
    }
    __builtin_amdgcn_sched_barrier(0);
    __builtin_amdgcn_s_barrier();                       // all waves' buf-ct data landed
    const char* base = (const char*)sm + ct * 16384;
    s16x8 af[4], bfr[4];
    #pragma unroll
    for (int mb = 0; mb < 4; mb++) af[mb] = *(const s16x8*)(base + aOff[mb]);
    #pragma unroll
    for (int nb = 0; nb < 4; nb++) bfr[nb] = *(const s16x8*)(base + bOff[nb]);
    __builtin_amdgcn_s_setprio(1);
    #pragma unroll
    for (int mb = 0; mb < 4; mb++)
      #pragma unroll
      for (int nb = 0; nb < 4; nb++)
        acc[mb][nb] = mfma16(af[mb], bfr[nb], acc[mb][nb]);
    __builtin_amdgcn_s_setprio(0);
  };

  STAGE(0);
  if (nkt == 32){
    for (int kt = 0; kt < 30; kt += 3){
      KITER(kt, 0, 1); KITER(kt + 1, 1, 2); KITER(kt + 2, 2, 0);
    }
    KITER(30, 0, 1); KITER(31, 1, 2);
  } else {
    for (int kt = 0; kt < 15; kt += 3){
      KITER(kt, 0, 1); KITER(kt + 1, 1, 2); KITER(kt + 2, 2, 0);
    }
    KITER(15, 0, 1);
  }

  if (z == 2){
    const float* bias = P.b2;
    __syncthreads();
    u16* Ot = sm;
    #pragma unroll
    for (int mb = 0; mb < 4; mb++){
      #pragma unroll
      for (int nb = 0; nb < 4; nb++){
        int colL = wn * 64 + nb * 16 + li;
        int rowB = wm * 64 + mb * 16 + lq * 4;
        float bcol = bias[n0 + colL];
        unsigned p01 = cvtpk(acc[mb][nb][0] + bcol, acc[mb][nb][1] + bcol);
        unsigned p23 = cvtpk(acc[mb][nb][2] + bcol, acc[mb][nb][3] + bcol);
        int ba = colL * 256 + ((rowB * 2) ^ ((colL & 7) << 4));
        *(unsigned*)((char*)Ot + ba) = p01;
        *(unsigned*)((char*)Ot + ba + 4) = p23;
      }
    }
    __syncthreads();
    int bq_ = m0 >> 11, srow0 = m0 & 2047;
    #pragma unroll
    for (int i = 0; i < 8; i++){
      int u = i * 256 + tid;
      int colL = u >> 4, sc = u & 15;
      int ba = colL * 256 + ((sc * 16) ^ ((colL & 7) << 4));
      u16x8 vv = *(const u16x8*)((char*)Ot + ba);
      *(u16x8*)(P.outV + (((size_t)(bq_ * 1024 + n0 + colL)) << 11) + srow0 + sc * 8) = vv;
    }
    return;
  }

  if (z == 3){
    float* Xo = (kbase == 0) ? P.outX0 : P.outX1;
    #pragma unroll
    for (int mb = 0; mb < 4; mb++){
      #pragma unroll
      for (int nb = 0; nb < 4; nb++){
        int col = n0 + wn * 64 + nb * 16 + li;
        #pragma unroll
        for (int r = 0; r < 4; r++){
          int row = m0 + wm * 64 + mb * 16 + lq * 4 + r;
          Xo[(size_t)row * 1024 + col] = acc[mb][nb][r];
        }
      }
    }
    return;
  }

  const float* bias = (z == 0) ? P.b0 : P.b1;
  #pragma unroll
  for (int mb = 0; mb < 4; mb++){
    #pragma unroll
    for (int nb = 0; nb < 4; nb++){
      int colL = wn * 64 + nb * 16 + li; int col = n0 + colL;
      float bcol = bias[col];
      #pragma unroll
      for (int r = 0; r < 4; r++){
        int row = m0 + wm * 64 + mb * 16 + lq * 4 + r;
        float v = acc[mb][nb][r] + bcol;
        if (z == 0){
          P.outQ[(size_t)row * 1024 + col] = f2bf(v * CKF);
        } else {
          v += P.ctx[(size_t)(row >> 11) * 1024 + col];
          P.outK[(size_t)row * 1024 + col] = f2bf(v);
        }
      }
    }
  }
}

// ---------------------------------------------------------------- flash attention (R8 structure,
// TRIPLE-buffered K/V/mask, ONE barrier per tile). 4 waves, 128 q-rows/block, grid (16,32).
__global__ __launch_bounds__(256) void attn_kernel(
    const u16* __restrict__ Qg, const u16* __restrict__ Kg, const u16* __restrict__ Vtg,
    const unsigned* __restrict__ mbits, u16* __restrict__ ctx2){
  // arena u16: 3 bufs x 8192 (K 0..4095, V 4096..8191) = 24576; masks u32 at u16 24576 (3x256 u32)
  __shared__ __align__(16) u16 arena[26112];
  int tid = threadIdx.x, lane = tid & 63, w = tid >> 6;
  int l31 = lane & 31, hi = lane >> 5;
  int r7 = l31 & 7;
  int orig = blockIdx.x + (blockIdx.y << 4);
  int swz = (orig & 7) * 64 + (orig >> 3);
  int q0 = (swz & 15) * 128, bh = swz >> 4, b = bh >> 4, h = bh & 15;
  int qr = w * 32 + l31;

  s16x8 qf[4];
  {
    const u16* qp = Qg + (size_t)(b * 2048 + q0 + qr) * 1024 + h * 64 + hi * 8;
    #pragma unroll
    for (int ks = 0; ks < 4; ks++)
      qf[ks] = *(const s16x8*)(qp + ks * 16);
  }
  s16x8 onesf;
  #pragma unroll
  for (int e = 0; e < 8; e++) onesf[e] = (short)0x3F80;
  f32x16 ZERO;
  #pragma unroll
  for (int r = 0; r < 16; r++) ZERO[r] = 0.f;

  int scolS = ((lane & 7) ^ (lane >> 3)) << 3;
  int rowS = w * 16 + (lane >> 3);
  const u16* kS0 = Kg + (size_t)(b * 2048 + rowS) * 1024 + h * 64 + scolS;
  const u16* kS1 = kS0 + (size_t)8 * 1024;
  const u16* vS0 = Vtg + (((size_t)(bh * 64 + rowS)) << 11) + scolS;
  const u16* vS1 = vS0 + ((size_t)8 << 11);
  int um = w * 64 + lane;
  const unsigned* mS = mbits + (size_t)(b * 2048 + q0 + (um >> 1)) * 64 + (um & 1);
  int kD0 = w * 1024, kD1 = w * 1024 + 512;

  int koff[2][4], voff[2][4];
  #pragma unroll
  for (int jj = 0; jj < 2; jj++)
    #pragma unroll
    for (int ks = 0; ks < 4; ks++){
      koff[jj][ks] = ((jj * 32 + l31) * 64 + (((ks * 2 + hi) ^ r7) << 3)) * 2;
      voff[jj][ks] = 8192 + ((jj * 32 + l31) * 64 + (((ks * 2 + hi) ^ r7) << 3)) * 2;
    }
  int mB = 49152 + qr * 8;   // byte offset of masks base (+ct*1024)

  auto STAGE = [&](int ct){
    u16* dst = &arena[ct * 8192];
    glds16(kS0, dst + kD0);
    glds16(kS1, dst + kD1);
    glds16(vS0, dst + 4096 + kD0);
    glds16(vS1, dst + 4096 + kD1);
    glds4(mS, (unsigned*)&arena[24576] + ct * 256 + w * 64);
    kS0 += (size_t)64 * 1024; kS1 += (size_t)64 * 1024;
    vS0 += 64; vS1 += 64; mS += 2;
  };

  f32x16 accO[2], accS;
  accO[0] = ZERO; accO[1] = ZERO; accS = ZERO;

  STAGE(0);

  auto ITER = [&](int t, int ct, int cn){
    if (t < 31){
      STAGE(cn);
      asm volatile("s_waitcnt vmcnt(5)" ::: "memory");
    } else {
      asm volatile("s_waitcnt vmcnt(0)" ::: "memory");
    }
    __builtin_amdgcn_sched_barrier(0);
    __builtin_amdgcn_s_barrier();
    const char* base = (const char*)arena + ct * 16384;

    f32x16 S[2];
    __builtin_amdgcn_s_setprio(1);
    #pragma unroll
    for (int jj = 0; jj < 2; jj++){
      S[jj] = ZERO;
      #pragma unroll
      for (int ks = 0; ks < 4; ks++){
        s16x8 kf = *(const s16x8*)(base + koff[jj][ks]);
        S[jj] = mfma32(kf, qf[ks], S[jj]);
      }
    }
    __builtin_amdgcn_s_setprio(0);

    uint2v mw = *(const uint2v*)((const char*)arena + mB + ct * 1024);
    unsigned mh0 = mw[0] >> (hi << 2), mh1 = mw[1] >> (hi << 2);
    #pragma unroll
    for (int jj = 0; jj < 2; jj++){
      unsigned mh = jj ? mh1 : mh0;
      #pragma unroll
      for (int rg = 0; rg < 16; rg++){
        int pos = (rg & 3) + ((rg >> 2) << 3);
        float pv = exp2a(S[jj][rg]);
        S[jj][rg] = ((mh >> pos) & 1u) ? pv : 0.f;
      }
    }

    s16x8 pf[4];
    #pragma unroll
    for (int jj = 0; jj < 2; jj++){
      #pragma unroll
      for (int hs = 0; hs < 2; hs++){
        int rb = hs * 8;
        unsigned A0 = cvtpk(S[jj][rb + 0], S[jj][rb + 1]);
        unsigned A1 = cvtpk(S[jj][rb + 2], S[jj][rb + 3]);
        unsigned B0 = cvtpk(S[jj][rb + 4], S[jj][rb + 5]);
        unsigned B1 = cvtpk(S[jj][rb + 6], S[jj][rb + 7]);
        uint2v r01 = __builtin_amdgcn_permlane32_swap(A0, B0, false, false);
        uint2v r23 = __builtin_amdgcn_permlane32_swap(A1, B1, false, false);
        uint4v uu = { r01[0], r23[0], r01[1], r23[1] };
        pf[jj * 2 + hs] = *(s16x8*)&uu;
      }
    }
    __builtin_amdgcn_s_setprio(1);
    #pragma unroll
    for (int c = 0; c < 4; c++){
      #pragma unroll
      for (int dh = 0; dh < 2; dh++){
        s16x8 vf = *(const s16x8*)(base + voff[dh][c]);
        accO[dh] = mfma32(vf, pf[c], accO[dh]);
      }
      accS = mfma32(onesf, pf[c], accS);
    }
    __builtin_amdgcn_s_setprio(0);
  };

  for (int t = 0; t < 30; t += 3){
    ITER(t, 0, 1); ITER(t + 1, 1, 2); ITER(t + 2, 2, 0);
  }
  ITER(30, 0, 1); ITER(31, 1, 2);

  __syncthreads();
  float lsum = accS[0];
  float inv = 1.f / lsum;
  u16* Ot = arena;
  #pragma unroll
  for (int dh = 0; dh < 2; dh++){
    #pragma unroll
    for (int rg = 0; rg < 16; rg += 2){
      int dk = dh * 32 + (rg & 3) + ((rg >> 2) << 3) + (hi << 2);
      unsigned pk = cvtpk(accO[dh][rg] * inv, accO[dh][rg + 1] * inv);
      *(unsigned*)&Ot[qr * 64 + (((dk >> 3) ^ (qr & 7)) << 3) + (dk & 7)] = pk;
    }
  }
  __syncthreads();
  #pragma unroll
  for (int i = 0; i < 4; i++){
    int u = i * 256 + tid, row = u >> 3, slot = u & 7;
    u16x8 vv = *(const u16x8*)&Ot[row * 64 + ((slot ^ (row & 7)) << 3)];
    *(u16x8*)(ctx2 + (size_t)(b * 2048 + q0 + row) * 1024 + h * 64 + slot * 8) = vv;
  }
}

// ---------------------------------------------------------------- LayerNorm of (X0 + X1 + query + bo)
__global__ __launch_bounds__(256) void ln_kernel(const float* __restrict__ X0,
                                                 const float* __restrict__ X1,
                                                 const float* __restrict__ qres,
                                                 const float* __restrict__ bo,
                                                 const float* __restrict__ g,
                                                 const float* __restrict__ bb,
                                                 float* __restrict__ out){
  size_t row = blockIdx.x;
  int tid = threadIdx.x;
  float4 a = *(const float4*)(X0 + row * 1024 + tid * 4);
  float4 c = *(const float4*)(X1 + row * 1024 + tid * 4);
  float4 q = *(const float4*)(qres + row * 1024 + tid * 4);
  float4 bv = *(const float4*)(bo + tid * 4);
  float4 v;
  v.x = a.x + c.x + q.x + bv.x;
  v.y = a.y + c.y + q.y + bv.y;
  v.z = a.z + c.z + q.z + bv.z;
  v.w = a.w + c.w + q.w + bv.w;
  float s = v.x + v.y + v.z + v.w;
  float s2 = v.x*v.x + v.y*v.y + v.z*v.z + v.w*v.w;
  #pragma unroll
  for (int o = 1; o < 64; o <<= 1){
    s += __shfl_xor(s, o, 64);
    s2 += __shfl_xor(s2, o, 64);
  }
  __shared__ float rs[4], rs2[4];
  int w = tid >> 6;
  if ((tid & 63) == 0){ rs[w] = s; rs2[w] = s2; }
  __syncthreads();
  s = rs[0] + rs[1] + rs[2] + rs[3];
  s2 = rs2[0] + rs2[1] + rs2[2] + rs2[3];
  float mu = s * (1.f / 1024.f);
  float var = s2 * (1.f / 1024.f) - mu * mu;
  float rstd = rsqrtf(var + 1e-5f);
  float4 gg = *(const float4*)(g + tid * 4);
  float4 bt = *(const float4*)(bb + tid * 4);
  float4 o;
  o.x = (v.x - mu) * rstd * gg.x + bt.x;
  o.y = (v.y - mu) * rstd * gg.y + bt.y;
  o.z = (v.z - mu) * rstd * gg.z + bt.z;
  o.w = (v.w - mu) * rstd * gg.w + bt.w;
  *(float4*)(out + row * 1024 + tid * 4) = o;
}

// ----------------------------------------------------------------
extern "C" void kernel_launch(void* const* d_in, const int* in_sizes, int n_in,
                              void* d_out, int out_size, void* d_ws, size_t ws_size,
                              hipStream_t stream){
  const float* query = (const float*)d_in[0];
  const float* key_  = (const float*)d_in[1];
  const float* value = (const float*)d_in[2];
  const int*   mask  = (const int*)d_in[3];
  const float* mc    = (const float*)d_in[4];
  const float* Wq = (const float*)d_in[5];  const float* bq = (const float*)d_in[6];
  const float* Wk = (const float*)d_in[7];  const float* bk = (const float*)d_in[8];
  const float* Wv = (const float*)d_in[9];  const float* bv = (const float*)d_in[10];
  const float* Wo = (const float*)d_in[11]; const float* bo = (const float*)d_in[12];
  const float* Wc = (const float*)d_in[13]; const float* bc = (const float*)d_in[14];
  const float* lng = (const float*)d_in[15]; const float* lnb = (const float*)d_in[16];
  float* outp = (float*)d_out;
  uint8_t* ws = (uint8_t*)d_ws;
  const size_t MB = (size_t)1 << 20;
  if (ws_size < 58 * MB) return;

  u16* q_bf = (u16*)(ws + 0);
  u16* k_bf = (u16*)(ws + 8 * MB);
  u16* v_bf = (u16*)(ws + 16 * MB);
  float* X0 = (float*)(ws + 8 * MB);
  u16* Qb   = (u16*)(ws + 24 * MB);
  u16* Kb   = (u16*)(ws + 32 * MB);
  float* X1 = (float*)(ws + 32 * MB);
  u16* Vt   = (u16*)(ws + 40 * MB);
  u16* Wqt  = (u16*)(ws + 48 * MB);
  u16* Wkt  = (u16*)(ws + 50 * MB);
  u16* Wvt  = (u16*)(ws + 52 * MB);
  u16* Wot  = (u16*)(ws + 54 * MB);
  unsigned* mbits = (unsigned*)(ws + 56 * MB);
  float* ctxf = (float*)(ws + 57 * MB);
  float* ctxpart = (float*)(ws + 57 * MB + 65536);
  u16* ctx2 = q_bf;

  PrepParams PP;
  PP.q = query; PP.k = key_; PP.v = value; PP.mask = mask; PP.mc = mc;
  PP.W0 = Wq; PP.W1 = Wk; PP.W2 = Wv; PP.W3 = Wo; PP.Wc = Wc;
  PP.qo = q_bf; PP.ko = k_bf; PP.vo = v_bf;
  PP.T0 = Wqt; PP.T1 = Wkt; PP.T2 = Wvt; PP.T3 = Wot;
  PP.bits = mbits; PP.part = ctxpart;
  prep_kernel<<<43024, 256, 0, stream>>>(PP);

  ctxred_kernel<<<2, 256, 0, stream>>>(ctxpart, bc, ctxf);

  GemmParams gp;
  gp.A0 = q_bf; gp.A1 = k_bf; gp.A2 = v_bf; gp.A3 = ctx2;
  gp.W0 = Wqt;  gp.W1 = Wkt;  gp.W2 = Wvt;  gp.W3 = Wot;
  gp.b0 = bq;   gp.b1 = bk;   gp.b2 = bv;
  gp.ctx = ctxf;
  gp.outQ = Qb; gp.outK = Kb; gp.outV = Vt; gp.outX0 = X0; gp.outX1 = X1;
  gp.which = -1;
  gemm_kernel<<<dim3(8, 32, 3), 256, 0, stream>>>(gp);

  attn_kernel<<<dim3(16, 32), 256, 0, stream>>>(Qb, Kb, Vt, mbits, ctx2);

  gp.which = 3;
  gemm_kernel<<<dim3(8, 32, 2), 256, 0, stream>>>(gp);

  ln_kernel<<<4096, 256, 0, stream>>>(X0, X1, query, bo, lng, lnb, outp);
}

// Round 16
// 145.864 us; speedup vs baseline: 1.5567x; 1.0493x over previous
//
#include <hip/hip_runtime.h>
#include <cstdint>

typedef unsigned short u16;
typedef __attribute__((ext_vector_type(4))) unsigned short us4;
typedef __attribute__((ext_vector_type(8))) short s16x8;
typedef __attribute__((ext_vector_type(8))) unsigned short u16x8;
typedef __attribute__((ext_vector_type(4))) float f32x4;
typedef __attribute__((ext_vector_type(16))) float f32x16;
typedef __attribute__((ext_vector_type(2))) unsigned uint2v;
typedef __attribute__((ext_vector_type(4))) unsigned uint4v;

#define CKF 0.18033688011f  // log2(e)/8, folded into Q projection

__device__ inline u16 f2bf(float f){
  union { float f; uint32_t u; } v; v.f = f;
  uint32_t r = v.u + 0x7fffu + ((v.u >> 16) & 1u);
  return (u16)(r >> 16);
}
__device__ inline float bf2f(u16 x){
  union { uint32_t u; float f; } v; v.u = ((uint32_t)x) << 16;
  return v.f;
}

__device__ inline f32x4 mfma16(s16x8 a, s16x8 b, f32x4 c){
  return __builtin_amdgcn_mfma_f32_16x16x32_bf16(a, b, c, 0, 0, 0);
}
__device__ inline f32x16 mfma32(s16x8 a, s16x8 b, f32x16 c){
  return __builtin_amdgcn_mfma_f32_32x32x16_bf16(a, b, c, 0, 0, 0);
}
__device__ inline unsigned cvtpk(float a, float b){
  unsigned r;
  asm("v_cvt_pk_bf16_f32 %0, %1, %2" : "=v"(r) : "v"(a), "v"(b));
  return r;
}
__device__ inline float exp2a(float x){
  float r;
  asm("v_exp_f32 %0, %1" : "=v"(r) : "v"(x));
  return r;
}
__device__ inline void glds16(const u16* g, u16* l){
  __builtin_amdgcn_global_load_lds((const __attribute__((address_space(1))) void*)g,
                                   (__attribute__((address_space(3))) void*)l, 16, 0, 0);
}
__device__ inline void glds4(const unsigned* g, unsigned* l){
  __builtin_amdgcn_global_load_lds((const __attribute__((address_space(1))) void*)g,
                                   (__attribute__((address_space(3))) void*)l, 4, 0, 0);
}

// ---------------------------------------------------------------- merged prep
struct PrepParams {
  const float* q; const float* k; const float* v;
  const int* mask; const float* mc;
  const float* W0; const float* W1; const float* W2; const float* W3;
  const float* Wc;
  u16* qo; u16* ko; u16* vo;
  u16* T0; u16* T1; u16* T2; u16* T3;
  unsigned* bits; float* part;
};

__global__ __launch_bounds__(256) void prep_kernel(PrepParams PP){
  __shared__ float shf[1056];
  int blk = blockIdx.x, tid = threadIdx.x;
  if (blk < 6144){
    int byy = blk >> 11, bxx = blk & 2047;
    const float* src = (byy == 0) ? PP.q : (byy == 1) ? PP.k : PP.v;
    u16* dst = (byy == 0) ? PP.qo : (byy == 1) ? PP.ko : PP.vo;
    size_t i = ((size_t)bxx * 256 + tid) * 8;
    float4 a = *(const float4*)(src + i);
    float4 b = *(const float4*)(src + i + 4);
    u16x8 o = { f2bf(a.x), f2bf(a.y), f2bf(a.z), f2bf(a.w),
                f2bf(b.x), f2bf(b.y), f2bf(b.z), f2bf(b.w) };
    *(u16x8*)(dst + i) = o;
  } else if (blk < 10240){
    int idx = blk - 6144;
    int bxx = idx & 31, byy = (idx >> 5) & 31, bzz = idx >> 10;
    const float* W = (bzz == 0) ? PP.W0 : (bzz == 1) ? PP.W1 : (bzz == 2) ? PP.W2 : PP.W3;
    u16* T = (bzz == 0) ? PP.T0 : (bzz == 1) ? PP.T1 : (bzz == 2) ? PP.T2 : PP.T3;
    float (*t)[33] = (float(*)[33])shf;
    int n0 = bxx * 32, k0 = byy * 32;
    int tx = tid & 31, ty = tid >> 5;
    #pragma unroll
    for (int j = 0; j < 4; j++)
      t[ty + j*8][tx] = W[(size_t)(k0 + ty + j*8) * 1024 + n0 + tx];
    __syncthreads();
    #pragma unroll
    for (int j = 0; j < 4; j++)
      T[(size_t)(n0 + ty + j*8) * 1024 + k0 + tx] = f2bf(t[tx][ty + j*8]);
  } else if (blk < 43008){
    size_t i = (size_t)(blk - 10240) * 256 + tid;
    int v = PP.mask[i];
    unsigned long long bal = __ballot(v != 0);
    int lane = tid & 63;
    if (lane == 0)       PP.bits[i >> 5] = (unsigned)bal;
    else if (lane == 32) PP.bits[i >> 5] = (unsigned)(bal >> 32);
  } else {
    int slice = blk - 43008;          // 0..15
    int k0 = slice * 64;
    float4 a0 = {0.f,0.f,0.f,0.f}, a1 = {0.f,0.f,0.f,0.f};
    const float* wp = PP.Wc + (size_t)k0 * 1024 + tid * 4;
    #pragma unroll 8
    for (int k = 0; k < 64; k++){
      float4 wv = *(const float4*)(wp + (size_t)k * 1024);
      float m0 = PP.mc[k0 + k], m1 = PP.mc[1024 + k0 + k];
      a0.x += m0 * wv.x; a0.y += m0 * wv.y; a0.z += m0 * wv.z; a0.w += m0 * wv.w;
      a1.x += m1 * wv.x; a1.y += m1 * wv.y; a1.z += m1 * wv.z; a1.w += m1 * wv.w;
    }
    *(float4*)(PP.part + ((size_t)slice * 2 + 0) * 1024 + tid * 4) = a0;
    *(float4*)(PP.part + ((size_t)slice * 2 + 1) * 1024 + tid * 4) = a1;
  }
}

// ---------------------------------------------------------------- GEMM (ctx reduce folded into z=1)
struct GemmParams {
  const u16* A0; const u16* A1; const u16* A2; const u16* A3;   // A3: which<0 -> smuggled bc ptr
  const u16* W0; const u16* W1; const u16* W2; const u16* W3;
  const float* b0; const float* b1; const float* b2;
  const float* part;
  u16* outQ; u16* outK; u16* outV; u16* outX0; u16* outX1;
  int which;
};

__global__ __launch_bounds__(256) void gemm_kernel(GemmParams P){
  int o = blockIdx.x + (blockIdx.y << 3) + (blockIdx.z << 8);
  int xcd = o & 7, j = o >> 3;
  int by = xcd + ((j & 3) << 3);
  int bx = (j >> 2) & 7;
  int bz = j >> 5;

  int z, kbase, nkt;
  const u16* A; const u16* W;
  if (P.which < 0){
    z = bz; kbase = 0; nkt = 32;
    if (z == 0){ A = P.A0; W = P.W0; }
    else if (z == 1){ A = P.A1; W = P.W1; }
    else { A = P.A2; W = P.W2; }
  } else {
    z = 3; kbase = bz * 512; nkt = 16;
    A = P.A3; W = P.W3;
  }
  int m0 = by * 128, n0 = bx * 128;
  __shared__ __align__(16) u16 sm[24576];
  int tid = threadIdx.x, lane = tid & 63, w = tid >> 6;
  int li = lane & 15, lq = lane >> 4;
  int wm = w >> 1, wn = w & 1;
  f32x4 zero = {0.f, 0.f, 0.f, 0.f};
  f32x4 acc[4][4];
  #pragma unroll
  for (int i = 0; i < 4; i++)
    #pragma unroll
    for (int jj = 0; jj < 4; jj++) acc[i][jj] = zero;

  int scolS = ((lane & 3) ^ ((lane >> 3) & 3)) << 3;
  int row0 = w * 16 + (lane >> 2);
  const u16* aS0 = A + (size_t)(m0 + row0) * 1024 + kbase + scolS;
  const u16* aS1 = aS0 + (size_t)64 * 1024;
  const u16* bS0 = W + (size_t)(n0 + row0) * 1024 + kbase + scolS;
  const u16* bS1 = bS0 + (size_t)64 * 1024;
  int aD0 = (w * 64) * 8, aD1 = (256 + w * 64) * 8;

  int aOff[4], bOff[4];
  #pragma unroll
  for (int mb = 0; mb < 4; mb++){
    int row = wm * 64 + mb * 16 + li;
    aOff[mb] = (row * 32 + ((lq ^ ((row >> 1) & 3)) << 3)) * 2;
  }
  #pragma unroll
  for (int nb = 0; nb < 4; nb++){
    int row = wn * 64 + nb * 16 + li;
    bOff[nb] = 8192 + (row * 32 + ((lq ^ ((row >> 1) & 3)) << 3)) * 2;
  }

  auto STAGE = [&](int ct){
    u16* Ab = &sm[ct * 8192];
    u16* Bb = &sm[ct * 8192 + 4096];
    glds16(aS0, Ab + aD0);
    glds16(aS1, Ab + aD1);
    glds16(bS0, Bb + aD0);
    glds16(bS1, Bb + aD1);
    aS0 += 32; aS1 += 32; bS0 += 32; bS1 += 32;
  };

  auto KITER = [&](int kt, int ct, int cn){
    if (kt + 1 < nkt){
      STAGE(cn);
      asm volatile("s_waitcnt vmcnt(4)" ::: "memory");
    } else {
      asm volatile("s_waitcnt vmcnt(0)" ::: "memory");
    }
    __builtin_amdgcn_sched_barrier(0);
    __builtin_amdgcn_s_barrier();
    const char* base = (const char*)sm + ct * 16384;
    s16x8 af[4], bfr[4];
    #pragma unroll
    for (int mb = 0; mb < 4; mb++) af[mb] = *(const s16x8*)(base + aOff[mb]);
    #pragma unroll
    for (int nb = 0; nb < 4; nb++) bfr[nb] = *(const s16x8*)(base + bOff[nb]);
    __builtin_amdgcn_s_setprio(1);
    #pragma unroll
    for (int mb = 0; mb < 4; mb++)
      #pragma unroll
      for (int nb = 0; nb < 4; nb++)
        acc[mb][nb] = mfma16(af[mb], bfr[nb], acc[mb][nb]);
    __builtin_amdgcn_s_setprio(0);
  };

  STAGE(0);
  if (nkt == 32){
    for (int kt = 0; kt < 30; kt += 3){
      KITER(kt, 0, 1); KITER(kt + 1, 1, 2); KITER(kt + 2, 2, 0);
    }
    KITER(30, 0, 1); KITER(31, 1, 2);
  } else {
    for (int kt = 0; kt < 15; kt += 3){
      KITER(kt, 0, 1); KITER(kt + 1, 1, 2); KITER(kt + 2, 2, 0);
    }
    KITER(15, 0, 1);
  }

  if (z == 2){
    const float* bias = P.b2;
    __syncthreads();
    u16* Ot = sm;
    #pragma unroll
    for (int mb = 0; mb < 4; mb++){
      #pragma unroll
      for (int nb = 0; nb < 4; nb++){
        int colL = wn * 64 + nb * 16 + li;
        int rowB = wm * 64 + mb * 16 + lq * 4;
        float bcol = bias[n0 + colL];
        unsigned p01 = cvtpk(acc[mb][nb][0] + bcol, acc[mb][nb][1] + bcol);
        unsigned p23 = cvtpk(acc[mb][nb][2] + bcol, acc[mb][nb][3] + bcol);
        int ba = colL * 256 + ((rowB * 2) ^ ((colL & 7) << 4));
        *(unsigned*)((char*)Ot + ba) = p01;
        *(unsigned*)((char*)Ot + ba + 4) = p23;
      }
    }
    __syncthreads();
    int bq_ = m0 >> 11, srow0 = m0 & 2047;
    #pragma unroll
    for (int i = 0; i < 8; i++){
      int u = i * 256 + tid;
      int colL = u >> 4, sc = u & 15;
      int ba = colL * 256 + ((sc * 16) ^ ((colL & 7) << 4));
      u16x8 vv = *(const u16x8*)((char*)Ot + ba);
      *(u16x8*)(P.outV + (((size_t)(bq_ * 1024 + n0 + colL)) << 11) + srow0 + sc * 8) = vv;
    }
    return;
  }

  if (z == 3){
    u16* Xo = (kbase == 0) ? P.outX0 : P.outX1;
    #pragma unroll
    for (int mb = 0; mb < 4; mb++){
      #pragma unroll
      for (int nb = 0; nb < 4; nb++){
        int col = n0 + wn * 64 + nb * 16 + li;
        #pragma unroll
        for (int r = 0; r < 4; r++){
          int row = m0 + wm * 64 + mb * 16 + lq * 4 + r;
          Xo[(size_t)row * 1024 + col] = f2bf(acc[mb][nb][r]);
        }
      }
    }
    return;
  }

  if (z == 1){
    const float* bcK = (const float*)P.A3;   // smuggled bc
    int bidx = m0 >> 11;
    float ctxl[4];
    #pragma unroll
    for (int nb = 0; nb < 4; nb++){
      int col = n0 + wn * 64 + nb * 16 + li;
      float s = P.b1[col] + bcK[col];
      #pragma unroll 4
      for (int sl = 0; sl < 16; sl++)
        s += P.part[((size_t)sl * 2 + bidx) * 1024 + col];
      ctxl[nb] = s;
    }
    #pragma unroll
    for (int mb = 0; mb < 4; mb++){
      #pragma unroll
      for (int nb = 0; nb < 4; nb++){
        int col = n0 + wn * 64 + nb * 16 + li;
        #pragma unroll
        for (int r = 0; r < 4; r++){
          int row = m0 + wm * 64 + mb * 16 + lq * 4 + r;
          P.outK[(size_t)row * 1024 + col] = f2bf(acc[mb][nb][r] + ctxl[nb]);
        }
      }
    }
    return;
  }

  const float* bias = P.b0;
  #pragma unroll
  for (int mb = 0; mb < 4; mb++){
    #pragma unroll
    for (int nb = 0; nb < 4; nb++){
      int colL = wn * 64 + nb * 16 + li; int col = n0 + colL;
      float bcol = bias[col];
      #pragma unroll
      for (int r = 0; r < 4; r++){
        int row = m0 + wm * 64 + mb * 16 + lq * 4 + r;
        P.outQ[(size_t)row * 1024 + col] = f2bf((acc[mb][nb][r] + bcol) * CKF);
      }
    }
  }
}

// ---------------------------------------------------------------- flash attention (R15 + micro-opts)
__global__ __launch_bounds__(256) void attn_kernel(
    const u16* __restrict__ Qg, const u16* __restrict__ Kg, const u16* __restrict__ Vtg,
    const unsigned* __restrict__ mbits, u16* __restrict__ ctx2){
  __shared__ __align__(16) u16 arena[26112];
  int tid = threadIdx.x, lane = tid & 63, w = tid >> 6;
  int l31 = lane & 31, hi = lane >> 5;
  int r7 = l31 & 7;
  int orig = blockIdx.x + (blockIdx.y << 4);
  int swz = (orig & 7) * 64 + (orig >> 3);
  int q0 = (swz & 15) * 128, bh = swz >> 4, b = bh >> 4, h = bh & 15;
  int qr = w * 32 + l31;

  s16x8 qf[4];
  {
    const u16* qp = Qg + (size_t)(b * 2048 + q0 + qr) * 1024 + h * 64 + hi * 8;
    #pragma unroll
    for (int ks = 0; ks < 4; ks++)
      qf[ks] = *(const s16x8*)(qp + ks * 16);
  }
  s16x8 onesf;
  #pragma unroll
  for (int e = 0; e < 8; e++) onesf[e] = (short)0x3F80;
  f32x16 ZERO;
  #pragma unroll
  for (int r = 0; r < 16; r++) ZERO[r] = 0.f;

  int scolS = ((lane & 7) ^ (lane >> 3)) << 3;
  int rowS = w * 16 + (lane >> 3);
  const u16* kS0 = Kg + (size_t)(b * 2048 + rowS) * 1024 + h * 64 + scolS;
  const u16* kS1 = kS0 + (size_t)8 * 1024;
  const u16* vS0 = Vtg + (((size_t)(bh * 64 + rowS)) << 11) + scolS;
  const u16* vS1 = vS0 + ((size_t)8 << 11);
  int um = w * 64 + lane;
  const unsigned* mS = mbits + (size_t)(b * 2048 + q0 + (um >> 1)) * 64 + (um & 1);
  int kD0 = w * 1024, kD1 = w * 1024 + 512;

  int koff[2][4], voff[2][4];
  #pragma unroll
  for (int jj = 0; jj < 2; jj++)
    #pragma unroll
    for (int ks = 0; ks < 4; ks++){
      koff[jj][ks] = ((jj * 32 + l31) * 64 + (((ks * 2 + hi) ^ r7) << 3)) * 2;
      voff[jj][ks] = 8192 + ((jj * 32 + l31) * 64 + (((ks * 2 + hi) ^ r7) << 3)) * 2;
    }
  int mB = 49152 + qr * 8;

  auto STAGE = [&](int ct){
    u16* dst = &arena[ct * 8192];
    glds16(kS0, dst + kD0);
    glds16(kS1, dst + kD1);
    glds16(vS0, dst + 4096 + kD0);
    glds16(vS1, dst + 4096 + kD1);
    glds4(mS, (unsigned*)&arena[24576] + ct * 256 + w * 64);
    kS0 += (size_t)64 * 1024; kS1 += (size_t)64 * 1024;
    vS0 += 64; vS1 += 64; mS += 2;
  };

  f32x16 accO[2], accS;
  accO[0] = ZERO; accO[1] = ZERO; accS = ZERO;

  STAGE(0);

  auto ITER = [&](int t, int ct, int cn){
    if (t < 31){
      STAGE(cn);
      asm volatile("s_waitcnt vmcnt(5)" ::: "memory");
    } else {
      asm volatile("s_waitcnt vmcnt(0)" ::: "memory");
    }
    __builtin_amdgcn_sched_barrier(0);
    __builtin_amdgcn_s_barrier();
    const char* base = (const char*)arena + ct * 16384;

    uint2v mw = *(const uint2v*)((const char*)arena + mB + ct * 1024);

    f32x16 S[2];
    __builtin_amdgcn_s_setprio(1);
    #pragma unroll
    for (int jj = 0; jj < 2; jj++){
      s16x8 kf0 = *(const s16x8*)(base + koff[jj][0]);
      S[jj] = mfma32(kf0, qf[0], ZERO);
      #pragma unroll
      for (int ks = 1; ks < 4; ks++){
        s16x8 kf = *(const s16x8*)(base + koff[jj][ks]);
        S[jj] = mfma32(kf, qf[ks], S[jj]);
      }
    }
    __builtin_amdgcn_s_setprio(0);

    unsigned mh0 = mw[0] >> (hi << 2), mh1 = mw[1] >> (hi << 2);
    #pragma unroll
    for (int jj = 0; jj < 2; jj++){
      unsigned mh = jj ? mh1 : mh0;
      #pragma unroll
      for (int rg = 0; rg < 16; rg++){
        int pos = (rg & 3) + ((rg >> 2) << 3);
        float pv = exp2a(S[jj][rg]);
        S[jj][rg] = ((mh >> pos) & 1u) ? pv : 0.f;
      }
    }

    s16x8 pf[4];
    #pragma unroll
    for (int jj = 0; jj < 2; jj++){
      #pragma unroll
      for (int hs = 0; hs < 2; hs++){
        int rb = hs * 8;
        unsigned A0 = cvtpk(S[jj][rb + 0], S[jj][rb + 1]);
        unsigned A1 = cvtpk(S[jj][rb + 2], S[jj][rb + 3]);
        unsigned B0 = cvtpk(S[jj][rb + 4], S[jj][rb + 5]);
        unsigned B1 = cvtpk(S[jj][rb + 6], S[jj][rb + 7]);
        uint2v r01 = __builtin_amdgcn_permlane32_swap(A0, B0, false, false);
        uint2v r23 = __builtin_amdgcn_permlane32_swap(A1, B1, false, false);
        uint4v uu = { r01[0], r23[0], r01[1], r23[1] };
        pf[jj * 2 + hs] = *(s16x8*)&uu;
      }
    }
    __builtin_amdgcn_s_setprio(1);
    #pragma unroll
    for (int c = 0; c < 4; c++){
      #pragma unroll
      for (int dh = 0; dh < 2; dh++){
        s16x8 vf = *(const s16x8*)(base + voff[dh][c]);
        accO[dh] = mfma32(vf, pf[c], accO[dh]);
      }
      accS = mfma32(onesf, pf[c], accS);
    }
    __builtin_amdgcn_s_setprio(0);
  };

  for (int t = 0; t < 30; t += 3){
    ITER(t, 0, 1); ITER(t + 1, 1, 2); ITER(t + 2, 2, 0);
  }
  ITER(30, 0, 1); ITER(31, 1, 2);

  __syncthreads();
  float lsum = accS[0];
  float inv = 1.f / lsum;
  u16* Ot = arena;
  #pragma unroll
  for (int dh = 0; dh < 2; dh++){
    #pragma unroll
    for (int rg = 0; rg < 16; rg += 2){
      int dk = dh * 32 + (rg & 3) + ((rg >> 2) << 3) + (hi << 2);
      unsigned pk = cvtpk(accO[dh][rg] * inv, accO[dh][rg + 1] * inv);
      *(unsigned*)&Ot[qr * 64 + (((dk >> 3) ^ (qr & 7)) << 3) + (dk & 7)] = pk;
    }
  }
  __syncthreads();
  #pragma unroll
  for (int i = 0; i < 4; i++){
    int u = i * 256 + tid, row = u >> 3, slot = u & 7;
    u16x8 vv = *(const u16x8*)&Ot[row * 64 + ((slot ^ (row & 7)) << 3)];
    *(u16x8*)(ctx2 + (size_t)(b * 2048 + q0 + row) * 1024 + h * 64 + slot * 8) = vv;
  }
}

// ---------------------------------------------------------------- LayerNorm of (X0b + X1b + query + bo)
__global__ __launch_bounds__(256) void ln_kernel(const u16* __restrict__ X0b,
                                                 const u16* __restrict__ X1b,
                                                 const float* __restrict__ qres,
                                                 const float* __restrict__ bo,
                                                 const float* __restrict__ g,
                                                 const float* __restrict__ bb,
                                                 float* __restrict__ out){
  size_t row = blockIdx.x;
  int tid = threadIdx.x;
  us4 a4 = *(const us4*)(X0b + row * 1024 + tid * 4);
  us4 c4 = *(const us4*)(X1b + row * 1024 + tid * 4);
  float4 q = *(const float4*)(qres + row * 1024 + tid * 4);
  float4 bv = *(const float4*)(bo + tid * 4);
  float4 v;
  v.x = bf2f(a4[0]) + bf2f(c4[0]) + q.x + bv.x;
  v.y = bf2f(a4[1]) + bf2f(c4[1]) + q.y + bv.y;
  v.z = bf2f(a4[2]) + bf2f(c4[2]) + q.z + bv.z;
  v.w = bf2f(a4[3]) + bf2f(c4[3]) + q.w + bv.w;
  float s = v.x + v.y + v.z + v.w;
  float s2 = v.x*v.x + v.y*v.y + v.z*v.z + v.w*v.w;
  #pragma unroll
  for (int o = 1; o < 64; o <<= 1){
    s += __shfl_xor(s, o, 64);
    s2 += __shfl_xor(s2, o, 64);
  }
  __shared__ float rs[4], rs2[4];
  int w = tid >> 6;
  if ((tid & 63) == 0){ rs[w] = s; rs2[w] = s2; }
  __syncthreads();
  s = rs[0] + rs[1] + rs[2] + rs[3];
  s2 = rs2[0] + rs2[1] + rs2[2] + rs2[3];
  float mu = s * (1.f / 1024.f);
  float var = s2 * (1.f / 1024.f) - mu * mu;
  float rstd = rsqrtf(var + 1e-5f);
  float4 gg = *(const float4*)(g + tid * 4);
  float4 bt = *(const float4*)(bb + tid * 4);
  float4 o;
  o.x = (v.x - mu) * rstd * gg.x + bt.x;
  o.y = (v.y - mu) * rstd * gg.y + bt.y;
  o.z = (v.z - mu) * rstd * gg.z + bt.z;
  o.w = (v.w - mu) * rstd * gg.w + bt.w;
  *(float4*)(out + row * 1024 + tid * 4) = o;
}

// ----------------------------------------------------------------
extern "C" void kernel_launch(void* const* d_in, const int* in_sizes, int n_in,
                              void* d_out, int out_size, void* d_ws, size_t ws_size,
                              hipStream_t stream){
  const float* query = (const float*)d_in[0];
  const float* key_  = (const float*)d_in[1];
  const float* value = (const float*)d_in[2];
  const int*   mask  = (const int*)d_in[3];
  const float* mc    = (const float*)d_in[4];
  const float* Wq = (const float*)d_in[5];  const float* bq = (const float*)d_in[6];
  const float* Wk = (const float*)d_in[7];  const float* bk = (const float*)d_in[8];
  const float* Wv = (const float*)d_in[9];  const float* bv = (const float*)d_in[10];
  const float* Wo = (const float*)d_in[11]; const float* bo = (const float*)d_in[12];
  const float* Wc = (const float*)d_in[13]; const float* bc = (const float*)d_in[14];
  const float* lng = (const float*)d_in[15]; const float* lnb = (const float*)d_in[16];
  float* outp = (float*)d_out;
  uint8_t* ws = (uint8_t*)d_ws;
  const size_t MB = (size_t)1 << 20;
  if (ws_size < 58 * MB) return;

  u16* q_bf = (u16*)(ws + 0);
  u16* k_bf = (u16*)(ws + 8 * MB);
  u16* v_bf = (u16*)(ws + 16 * MB);
  u16* X0b  = (u16*)(ws + 8 * MB);   // overlays k_bf (dead after QKV GEMM)
  u16* Qb   = (u16*)(ws + 24 * MB);
  u16* Kb   = (u16*)(ws + 32 * MB);
  u16* X1b  = (u16*)(ws + 32 * MB);  // overlays Kb (dead after attn)
  u16* Vt   = (u16*)(ws + 40 * MB);
  u16* Wqt  = (u16*)(ws + 48 * MB);
  u16* Wkt  = (u16*)(ws + 50 * MB);
  u16* Wvt  = (u16*)(ws + 52 * MB);
  u16* Wot  = (u16*)(ws + 54 * MB);
  unsigned* mbits = (unsigned*)(ws + 56 * MB);
  float* ctxpart = (float*)(ws + 57 * MB);
  u16* ctx2 = q_bf;

  PrepParams PP;
  PP.q = query; PP.k = key_; PP.v = value; PP.mask = mask; PP.mc = mc;
  PP.W0 = Wq; PP.W1 = Wk; PP.W2 = Wv; PP.W3 = Wo; PP.Wc = Wc;
  PP.qo = q_bf; PP.ko = k_bf; PP.vo = v_bf;
  PP.T0 = Wqt; PP.T1 = Wkt; PP.T2 = Wvt; PP.T3 = Wot;
  PP.bits = mbits; PP.part = ctxpart;
  prep_kernel<<<43024, 256, 0, stream>>>(PP);

  GemmParams gp;
  gp.A0 = q_bf; gp.A1 = k_bf; gp.A2 = v_bf; gp.A3 = (const u16*)bc;  // bc smuggled for z=1 fold
  gp.W0 = Wqt;  gp.W1 = Wkt;  gp.W2 = Wvt;  gp.W3 = Wot;
  gp.b0 = bq;   gp.b1 = bk;   gp.b2 = bv;
  gp.part = ctxpart;
  gp.outQ = Qb; gp.outK = Kb; gp.outV = Vt; gp.outX0 = X0b; gp.outX1 = X1b;
  gp.which = -1;
  gemm_kernel<<<dim3(8, 32, 3), 256, 0, stream>>>(gp);

  attn_kernel<<<dim3(16, 32), 256, 0, stream>>>(Qb, Kb, Vt, mbits, ctx2);

  gp.A3 = ctx2;
  gp.which = 3;
  gemm_kernel<<<dim3(8, 32, 2), 256, 0, stream>>>(gp);

  ln_kernel<<<4096, 256, 0, stream>>>(X0b, X1b, query, bo, lng, lnb, outp);
}